// Round 3
// baseline (9431.842 us; speedup 1.0000x reference)
//
#include <hip/hip_runtime.h>
#include <math.h>

#define TT 64
#define BB 256
#define OBS 512
#define ACTN 16
#define EMB 512
#define HID 1024
#define NCAT 32
#define NCLS 32
#define ZD 1024
#define G3 3072

typedef short s16x8 __attribute__((ext_vector_type(8)));
typedef float floatx4 __attribute__((ext_vector_type(4)));

__device__ __forceinline__ unsigned short f2bf(float f) {
    unsigned int u = __float_as_uint(f);
    unsigned int r = (u + 0x7fffu + ((u >> 16) & 1u)) >> 16;
    return (unsigned short)r;
}
__device__ __forceinline__ float bf2f(unsigned short h) {
    return __uint_as_float(((unsigned int)h) << 16);
}
__device__ __forceinline__ float elu1(float v) {
    return v > 0.f ? v : (expf(v) - 1.f);
}
__device__ __forceinline__ float sigm(float v) {
    return 1.f / (1.f + expf(-v));
}

// ---------------------------------------------------------------- one-hot -> index
__global__ void k_idx(const float* __restrict__ obs, const float* __restrict__ act,
                      int* __restrict__ obs_idx, int* __restrict__ act_idx) {
    int wave = (blockIdx.x * blockDim.x + threadIdx.x) >> 6;
    int lane = threadIdx.x & 63;
    if (wave >= TT * BB) return;
    const float* o = obs + (size_t)wave * OBS;
    int found = -1;
    #pragma unroll
    for (int j = 0; j < 8; ++j) {
        float v = o[lane + 64 * j];
        if (v > 0.5f) found = lane + 64 * j;
    }
    unsigned long long m = __ballot(found >= 0);
    int src = __ffsll(m) - 1;
    int oidx = __shfl(found, src);
    int af = -1;
    if (lane < ACTN) {
        float v = act[(size_t)wave * ACTN + lane];
        if (v > 0.5f) af = lane;
    }
    unsigned long long m2 = __ballot(af >= 0);
    int src2 = __ffsll(m2) - 1;
    int aidx = __shfl(af, src2);
    if (lane == 0) { obs_idx[wave] = oidx; act_idx[wave] = aidx; }
}

// ---------------------------------------------------------------- transpose fp32 -> bf16
// out[c*ldo + ko + r] = in[r*instride + c]; grid (cols/32, rows/32), block (32,8)
__global__ void k_transp(const float* __restrict__ in, int instride,
                         unsigned short* __restrict__ out, int ldo, int ko) {
    __shared__ float t[32][33];
    int c0 = blockIdx.x * 32, r0 = blockIdx.y * 32;
    int tx = threadIdx.x, ty = threadIdx.y;
    #pragma unroll
    for (int i = 0; i < 4; ++i)
        t[ty + 8 * i][tx] = in[(size_t)(r0 + ty + 8 * i) * instride + c0 + tx];
    __syncthreads();
    #pragma unroll
    for (int i = 0; i < 4; ++i)
        out[(size_t)(c0 + ty + 8 * i) * ldo + ko + r0 + tx] = f2bf(t[tx][ty + 8 * i]);
}

// ---------------------------------------------------------------- pack dec/head biases
__global__ void k_pack_bias(const float* bd1, const float* br1, const float* bc1,
                            float* __restrict__ out) {
    int i = threadIdx.x;
    if (i < 64) out[i] = bd1[i];
    else if (i < 128) out[i] = br1[i - 64];
    else out[i] = bc1[i - 128];
}

// ---------------------------------------------------------------- e1 = elu(We1[oi] + be1) bf16
__global__ void k_e1(const int* __restrict__ obs_idx, const float* __restrict__ We1,
                     const float* __restrict__ be1, unsigned short* __restrict__ e1) {
    int g = blockIdx.x * 256 + threadIdx.x;
    int s = g >> 6, k = g & 63;
    float v = We1[obs_idx[s] * 64 + k] + be1[k];
    e1[g] = f2bf(elu1(v));
}

// ---------------------------------------------------------------- generic MFMA GEMM (deferred/batched)
struct MJob {
    const unsigned short* X; int ldx;
    const unsigned short* WT;
    const float* bias;
    const unsigned short* addb;
    void* out; int ldo;
    int N, K, flags;              // 1=elu, 2=bf16 out, 4=addb
};

__global__ __launch_bounds__(256) void mfma_gemm(MJob j) {
    __shared__ unsigned short Xs[64][40];
    __shared__ unsigned short Ns[64][40];
    int tid = threadIdx.x;
    int m0 = blockIdx.y * 64, n0 = blockIdx.x * 64;
    int r = tid >> 2, p = (tid & 3) * 8;
    const unsigned short* xg = j.X + (size_t)(m0 + r) * j.ldx + p;
    const unsigned short* wg = j.WT + (size_t)(n0 + r) * j.K + p;
    int lane = tid & 63, wv = tid >> 6;
    int wm = (wv & 1) * 32, wn = (wv >> 1) * 32;
    int mi = lane & 15, q = lane >> 4;
    floatx4 acc00 = {0.f, 0.f, 0.f, 0.f};
    floatx4 acc01 = acc00, acc10 = acc00, acc11 = acc00;
    for (int kt = 0; kt < j.K; kt += 32) {
        *(float4*)&Xs[r][p] = *(const float4*)(xg + kt);
        *(float4*)&Ns[r][p] = *(const float4*)(wg + kt);
        __syncthreads();
        s16x8 a0 = *(const s16x8*)&Xs[wm + mi][q * 8];
        s16x8 a1 = *(const s16x8*)&Xs[wm + 16 + mi][q * 8];
        s16x8 b0 = *(const s16x8*)&Ns[wn + mi][q * 8];
        s16x8 b1 = *(const s16x8*)&Ns[wn + 16 + mi][q * 8];
        acc00 = __builtin_amdgcn_mfma_f32_16x16x32_bf16(a0, b0, acc00, 0, 0, 0);
        acc01 = __builtin_amdgcn_mfma_f32_16x16x32_bf16(a0, b1, acc01, 0, 0, 0);
        acc10 = __builtin_amdgcn_mfma_f32_16x16x32_bf16(a1, b0, acc10, 0, 0, 0);
        acc11 = __builtin_amdgcn_mfma_f32_16x16x32_bf16(a1, b1, acc11, 0, 0, 0);
        __syncthreads();
    }
    #pragma unroll
    for (int i = 0; i < 2; ++i) {
        #pragma unroll
        for (int jj = 0; jj < 2; ++jj) {
            floatx4 a = (i == 0) ? ((jj == 0) ? acc00 : acc01)
                                 : ((jj == 0) ? acc10 : acc11);
            int col = n0 + wn + jj * 16 + mi;
            float badd = j.bias ? j.bias[col] : 0.f;
            #pragma unroll
            for (int rg = 0; rg < 4; ++rg) {
                int row = m0 + wm + i * 16 + q * 4 + rg;
                float v = a[rg] + badd;
                if (j.flags & 4) v += bf2f(j.addb[(size_t)row * j.N + col]);
                if (j.flags & 1) v = elu1(v);
                if (j.flags & 2)
                    ((unsigned short*)j.out)[(size_t)row * j.ldo + col] = f2bf(v);
                else
                    ((float*)j.out)[(size_t)row * j.ldo + col] = v;
            }
        }
    }
}

// ---------------------------------------------------------------- fused [h|z]@Wcat + GRU
// WcatT[3072][2048]: row g*1024+j, cols 0..1023 = Wh[k][g*1024+j], 1024..2047 = Wi[k][g*1024+j]
// grid (16 j-tiles, 4 row-tiles), 256 thr
__global__ __launch_bounds__(256) void k_scan1(
    const unsigned short* __restrict__ xz_prev, const unsigned short* __restrict__ WcatT,
    const float* __restrict__ Wi, const float* __restrict__ bi, const float* __restrict__ bh,
    const int* __restrict__ act_t, float* __restrict__ h_st,
    unsigned short* __restrict__ xz_cur) {
    __shared__ unsigned short Xs[64][136];
    __shared__ unsigned short Ws[3][64][136];
    int tid = threadIdx.x;
    int j0 = blockIdx.x * 64, m0 = blockIdx.y * 64;
    int r = tid >> 2, pp = (tid & 3) * 8;
    const unsigned short* xg = xz_prev + (size_t)(m0 + r) * 2048 + pp;
    const unsigned short* wg0 = WcatT + (size_t)(j0 + r) * 2048 + pp;
    const unsigned short* wg1 = wg0 + (size_t)1024 * 2048;
    const unsigned short* wg2 = wg1 + (size_t)1024 * 2048;
    int lane = tid & 63, wv = tid >> 6;
    int wm = (wv & 1) * 32, wn = (wv >> 1) * 32;
    int mi = lane & 15, q = lane >> 4;
    floatx4 z4 = {0.f, 0.f, 0.f, 0.f};
    floatx4 aR[2][2] = {{z4, z4}, {z4, z4}};
    floatx4 aU[2][2] = {{z4, z4}, {z4, z4}};
    floatx4 aH[2][2] = {{z4, z4}, {z4, z4}};   // h@Wh_n
    floatx4 aI[2][2] = {{z4, z4}, {z4, z4}};   // z@Wi_n
    float4 xv[4], wv0[4], wv1[4], wv2[4];
    #pragma unroll
    for (int c = 0; c < 4; ++c) {
        xv[c]  = *(const float4*)(xg  + 32 * c);
        wv0[c] = *(const float4*)(wg0 + 32 * c);
        wv1[c] = *(const float4*)(wg1 + 32 * c);
        wv2[c] = *(const float4*)(wg2 + 32 * c);
    }
    for (int rd = 0; rd < 16; ++rd) {
        __syncthreads();
        #pragma unroll
        for (int c = 0; c < 4; ++c) {
            *(float4*)&Xs[r][pp + 32 * c]    = xv[c];
            *(float4*)&Ws[0][r][pp + 32 * c] = wv0[c];
            *(float4*)&Ws[1][r][pp + 32 * c] = wv1[c];
            *(float4*)&Ws[2][r][pp + 32 * c] = wv2[c];
        }
        __syncthreads();
        if (rd < 15) {
            int kt = (rd + 1) * 128;
            #pragma unroll
            for (int c = 0; c < 4; ++c) {
                xv[c]  = *(const float4*)(xg  + kt + 32 * c);
                wv0[c] = *(const float4*)(wg0 + kt + 32 * c);
                wv1[c] = *(const float4*)(wg1 + kt + 32 * c);
                wv2[c] = *(const float4*)(wg2 + kt + 32 * c);
            }
        }
        bool hph = rd < 8;
        #pragma unroll
        for (int c = 0; c < 4; ++c) {
            s16x8 a0 = *(const s16x8*)&Xs[wm + mi][c * 32 + q * 8];
            s16x8 a1 = *(const s16x8*)&Xs[wm + 16 + mi][c * 32 + q * 8];
            s16x8 b0 = *(const s16x8*)&Ws[0][wn + mi][c * 32 + q * 8];
            s16x8 b1 = *(const s16x8*)&Ws[0][wn + 16 + mi][c * 32 + q * 8];
            aR[0][0] = __builtin_amdgcn_mfma_f32_16x16x32_bf16(a0, b0, aR[0][0], 0, 0, 0);
            aR[0][1] = __builtin_amdgcn_mfma_f32_16x16x32_bf16(a0, b1, aR[0][1], 0, 0, 0);
            aR[1][0] = __builtin_amdgcn_mfma_f32_16x16x32_bf16(a1, b0, aR[1][0], 0, 0, 0);
            aR[1][1] = __builtin_amdgcn_mfma_f32_16x16x32_bf16(a1, b1, aR[1][1], 0, 0, 0);
            b0 = *(const s16x8*)&Ws[1][wn + mi][c * 32 + q * 8];
            b1 = *(const s16x8*)&Ws[1][wn + 16 + mi][c * 32 + q * 8];
            aU[0][0] = __builtin_amdgcn_mfma_f32_16x16x32_bf16(a0, b0, aU[0][0], 0, 0, 0);
            aU[0][1] = __builtin_amdgcn_mfma_f32_16x16x32_bf16(a0, b1, aU[0][1], 0, 0, 0);
            aU[1][0] = __builtin_amdgcn_mfma_f32_16x16x32_bf16(a1, b0, aU[1][0], 0, 0, 0);
            aU[1][1] = __builtin_amdgcn_mfma_f32_16x16x32_bf16(a1, b1, aU[1][1], 0, 0, 0);
            b0 = *(const s16x8*)&Ws[2][wn + mi][c * 32 + q * 8];
            b1 = *(const s16x8*)&Ws[2][wn + 16 + mi][c * 32 + q * 8];
            if (hph) {
                aH[0][0] = __builtin_amdgcn_mfma_f32_16x16x32_bf16(a0, b0, aH[0][0], 0, 0, 0);
                aH[0][1] = __builtin_amdgcn_mfma_f32_16x16x32_bf16(a0, b1, aH[0][1], 0, 0, 0);
                aH[1][0] = __builtin_amdgcn_mfma_f32_16x16x32_bf16(a1, b0, aH[1][0], 0, 0, 0);
                aH[1][1] = __builtin_amdgcn_mfma_f32_16x16x32_bf16(a1, b1, aH[1][1], 0, 0, 0);
            } else {
                aI[0][0] = __builtin_amdgcn_mfma_f32_16x16x32_bf16(a0, b0, aI[0][0], 0, 0, 0);
                aI[0][1] = __builtin_amdgcn_mfma_f32_16x16x32_bf16(a0, b1, aI[0][1], 0, 0, 0);
                aI[1][0] = __builtin_amdgcn_mfma_f32_16x16x32_bf16(a1, b0, aI[1][0], 0, 0, 0);
                aI[1][1] = __builtin_amdgcn_mfma_f32_16x16x32_bf16(a1, b1, aI[1][1], 0, 0, 0);
            }
        }
    }
    // epilogue: GRU
    int arowv[2][4];
    #pragma unroll
    for (int i = 0; i < 2; ++i)
        #pragma unroll
        for (int rg = 0; rg < 4; ++rg)
            arowv[i][rg] = 1024 + act_t[m0 + wm + i * 16 + q * 4 + rg];
    #pragma unroll
    for (int jj = 0; jj < 2; ++jj) {
        int j = j0 + wn + jj * 16 + mi;
        float bR = bi[j] + bh[j];
        float bU = bi[1024 + j] + bh[1024 + j];
        float bIN = bi[2048 + j];
        float bHN = bh[2048 + j];
        #pragma unroll
        for (int i = 0; i < 2; ++i) {
            #pragma unroll
            for (int rg = 0; rg < 4; ++rg) {
                int row = m0 + wm + i * 16 + q * 4 + rg;
                const float* wa = Wi + (size_t)arowv[i][rg] * G3;
                float rr = sigm(aR[i][jj][rg] + bR + wa[j]);
                float uu = sigm(aU[i][jj][rg] + bU + wa[1024 + j]);
                float inv = aI[i][jj][rg] + bIN + wa[2048 + j];
                float hnv = aH[i][jj][rg] + bHN;
                float nn = tanhf(inv + rr * hnv);
                float hp = h_st[(size_t)row * HID + j];
                float hnew = (1.f - uu) * nn + uu * hp;
                h_st[(size_t)row * HID + j] = hnew;
                xz_cur[(size_t)row * 2048 + j] = f2bf(hnew);
            }
        }
    }
}

// ---------------------------------------------------------------- post1 = elu(h @ Wq1a + Eq_t)
__global__ __launch_bounds__(256) void k_post1(
    const unsigned short* __restrict__ xz_cur, const unsigned short* __restrict__ Wq1aT,
    const unsigned short* __restrict__ Eq_t, unsigned short* __restrict__ post1) {
    __shared__ unsigned short Xs[64][136];
    __shared__ unsigned short Ns[64][136];
    int tid = threadIdx.x;
    int n0 = blockIdx.x * 64, m0 = blockIdx.y * 64;
    int r = tid >> 2, pp = (tid & 3) * 8;
    const unsigned short* xg = xz_cur + (size_t)(m0 + r) * 2048 + pp;
    const unsigned short* wg = Wq1aT + (size_t)(n0 + r) * 1024 + pp;
    int lane = tid & 63, wv = tid >> 6;
    int wm = (wv & 1) * 32, wn = (wv >> 1) * 32;
    int mi = lane & 15, q = lane >> 4;
    floatx4 z4 = {0.f, 0.f, 0.f, 0.f};
    floatx4 acc[2][2] = {{z4, z4}, {z4, z4}};
    float4 xv[4], wvv[4];
    #pragma unroll
    for (int c = 0; c < 4; ++c) {
        xv[c] = *(const float4*)(xg + 32 * c);
        wvv[c] = *(const float4*)(wg + 32 * c);
    }
    for (int rd = 0; rd < 8; ++rd) {
        __syncthreads();
        #pragma unroll
        for (int c = 0; c < 4; ++c) {
            *(float4*)&Xs[r][pp + 32 * c] = xv[c];
            *(float4*)&Ns[r][pp + 32 * c] = wvv[c];
        }
        __syncthreads();
        if (rd < 7) {
            int kt = (rd + 1) * 128;
            #pragma unroll
            for (int c = 0; c < 4; ++c) {
                xv[c] = *(const float4*)(xg + kt + 32 * c);
                wvv[c] = *(const float4*)(wg + kt + 32 * c);
            }
        }
        #pragma unroll
        for (int c = 0; c < 4; ++c) {
            s16x8 a0 = *(const s16x8*)&Xs[wm + mi][c * 32 + q * 8];
            s16x8 a1 = *(const s16x8*)&Xs[wm + 16 + mi][c * 32 + q * 8];
            s16x8 b0 = *(const s16x8*)&Ns[wn + mi][c * 32 + q * 8];
            s16x8 b1 = *(const s16x8*)&Ns[wn + 16 + mi][c * 32 + q * 8];
            acc[0][0] = __builtin_amdgcn_mfma_f32_16x16x32_bf16(a0, b0, acc[0][0], 0, 0, 0);
            acc[0][1] = __builtin_amdgcn_mfma_f32_16x16x32_bf16(a0, b1, acc[0][1], 0, 0, 0);
            acc[1][0] = __builtin_amdgcn_mfma_f32_16x16x32_bf16(a1, b0, acc[1][0], 0, 0, 0);
            acc[1][1] = __builtin_amdgcn_mfma_f32_16x16x32_bf16(a1, b1, acc[1][1], 0, 0, 0);
        }
    }
    #pragma unroll
    for (int i = 0; i < 2; ++i)
        #pragma unroll
        for (int jj = 0; jj < 2; ++jj) {
            int col = n0 + wn + jj * 16 + mi;
            #pragma unroll
            for (int rg = 0; rg < 4; ++rg) {
                int row = m0 + wm + i * 16 + q * 4 + rg;
                float v = acc[i][jj][rg] + bf2f(Eq_t[(size_t)row * 1024 + col]);
                post1[(size_t)row * 1024 + col] = f2bf(elu1(v));
            }
        }
}

// ---------------------------------------------------------------- postL + fused gumbel sample
__global__ __launch_bounds__(256) void k_postL(
    const unsigned short* __restrict__ post1, const unsigned short* __restrict__ Wq2T,
    const float* __restrict__ bq2, const float* __restrict__ gum_t,
    unsigned short* __restrict__ postL_t, unsigned short* __restrict__ xz_cur) {
    __shared__ unsigned short Xs[64][136];
    __shared__ unsigned short Ns[64][136];
    int tid = threadIdx.x;
    int n0 = blockIdx.x * 64, m0 = blockIdx.y * 64;
    int r = tid >> 2, pp = (tid & 3) * 8;
    const unsigned short* xg = post1 + (size_t)(m0 + r) * 1024 + pp;
    const unsigned short* wg = Wq2T + (size_t)(n0 + r) * 1024 + pp;
    int lane = tid & 63, wv = tid >> 6;
    int wm = (wv & 1) * 32, wn = (wv >> 1) * 32;
    int mi = lane & 15, q = lane >> 4;
    floatx4 z4 = {0.f, 0.f, 0.f, 0.f};
    floatx4 acc[2][2] = {{z4, z4}, {z4, z4}};
    float4 xv[4], wvv[4];
    #pragma unroll
    for (int c = 0; c < 4; ++c) {
        xv[c] = *(const float4*)(xg + 32 * c);
        wvv[c] = *(const float4*)(wg + 32 * c);
    }
    for (int rd = 0; rd < 8; ++rd) {
        __syncthreads();
        #pragma unroll
        for (int c = 0; c < 4; ++c) {
            *(float4*)&Xs[r][pp + 32 * c] = xv[c];
            *(float4*)&Ns[r][pp + 32 * c] = wvv[c];
        }
        __syncthreads();
        if (rd < 7) {
            int kt = (rd + 1) * 128;
            #pragma unroll
            for (int c = 0; c < 4; ++c) {
                xv[c] = *(const float4*)(xg + kt + 32 * c);
                wvv[c] = *(const float4*)(wg + kt + 32 * c);
            }
        }
        #pragma unroll
        for (int c = 0; c < 4; ++c) {
            s16x8 a0 = *(const s16x8*)&Xs[wm + mi][c * 32 + q * 8];
            s16x8 a1 = *(const s16x8*)&Xs[wm + 16 + mi][c * 32 + q * 8];
            s16x8 b0 = *(const s16x8*)&Ns[wn + mi][c * 32 + q * 8];
            s16x8 b1 = *(const s16x8*)&Ns[wn + 16 + mi][c * 32 + q * 8];
            acc[0][0] = __builtin_amdgcn_mfma_f32_16x16x32_bf16(a0, b0, acc[0][0], 0, 0, 0);
            acc[0][1] = __builtin_amdgcn_mfma_f32_16x16x32_bf16(a0, b1, acc[0][1], 0, 0, 0);
            acc[1][0] = __builtin_amdgcn_mfma_f32_16x16x32_bf16(a1, b0, acc[1][0], 0, 0, 0);
            acc[1][1] = __builtin_amdgcn_mfma_f32_16x16x32_bf16(a1, b1, acc[1][1], 0, 0, 0);
        }
    }
    // bias + store postL bf16
    float bA = bq2[n0 + wn + mi];
    float bB = bq2[n0 + wn + 16 + mi];
    #pragma unroll
    for (int i = 0; i < 2; ++i)
        #pragma unroll
        for (int jj = 0; jj < 2; ++jj) {
            int col = n0 + wn + jj * 16 + mi;
            float bb = jj ? bB : bA;
            #pragma unroll
            for (int rg = 0; rg < 4; ++rg) {
                acc[i][jj][rg] += bb;
                int row = m0 + wm + i * 16 + q * 4 + rg;
                postL_t[(size_t)row * 1024 + col] = f2bf(acc[i][jj][rg]);
            }
        }
    // gumbel-argmax over this wave's category (32 cols = one cat), write one-hot z
    int cat = (n0 + wn) >> 5;
    #pragma unroll
    for (int i = 0; i < 2; ++i) {
        #pragma unroll
        for (int rg = 0; rg < 4; ++rg) {
            int row = m0 + wm + i * 16 + q * 4 + rg;
            const float* gr = gum_t + (size_t)row * 1024 + cat * 32;
            float v0 = acc[i][0][rg] + gr[mi];
            float v1 = acc[i][1][rg] + gr[16 + mi];
            float bv; int cls;
            if (v1 > v0) { bv = v1; cls = 16 + mi; } else { bv = v0; cls = mi; }
            #pragma unroll
            for (int off = 1; off < 16; off <<= 1) {
                float ov = __shfl_xor(bv, off);
                int oc = __shfl_xor(cls, off);
                if (ov > bv || (ov == bv && oc < cls)) { bv = ov; cls = oc; }
            }
            unsigned short* zo = xz_cur + (size_t)row * 2048 + 1024 + cat * 32;
            zo[mi] = (mi == cls) ? 0x3F80 : 0;
            zo[16 + mi] = (16 + mi == cls) ? 0x3F80 : 0;
        }
    }
}

// ---------------------------------------------------------------- KL (deferred, all t)
__global__ void k_kl(const unsigned short* __restrict__ postL,
                     const unsigned short* __restrict__ priorL,
                     float* __restrict__ kl_acc) {
    int g = blockIdx.x * 256 + threadIdx.x;
    int sidx = g >> 5, cat = g & 31;
    const unsigned short* ql = postL + (size_t)sidx * ZD + cat * NCLS;
    const unsigned short* pl = priorL + (size_t)sidx * ZD + cat * NCLS;
    float vq[32], vp[32];
    float mq = -1e30f, mp = -1e30f;
    #pragma unroll
    for (int i = 0; i < NCLS; ++i) {
        vq[i] = bf2f(ql[i]); vp[i] = bf2f(pl[i]);
        mq = fmaxf(mq, vq[i]); mp = fmaxf(mp, vp[i]);
    }
    float sq = 0.f, sp = 0.f;
    #pragma unroll
    for (int i = 0; i < NCLS; ++i) { sq += expf(vq[i] - mq); sp += expf(vp[i] - mp); }
    float lseq = mq + logf(sq), lsep = mp + logf(sp);
    float kl = 0.f;
    #pragma unroll
    for (int i = 0; i < NCLS; ++i) {
        float lpq = vq[i] - lseq;
        kl += expf(lpq) * (lpq - (vp[i] - lsep));
    }
    __shared__ float red[256];
    red[threadIdx.x] = kl;
    __syncthreads();
    for (int s = 128; s > 0; s >>= 1) {
        if ((int)threadIdx.x < s) red[threadIdx.x] += red[threadIdx.x + s];
        __syncthreads();
    }
    if (threadIdx.x == 0) atomicAdd(&kl_acc[sidx >> 8], red[0]);
}

// ---------------------------------------------------------------- CE over 512 logits
__global__ void k_ce(const unsigned short* __restrict__ logits,
                     const int* __restrict__ obs_idx, float* __restrict__ ce_acc) {
    int s = (blockIdx.x * 256 + threadIdx.x) >> 6;
    int lane = threadIdx.x & 63;
    union { float4 f4; unsigned short u[8]; } raw;
    raw.f4 = *(const float4*)(logits + (size_t)s * OBS + lane * 8);
    float v[8];
    float m = -1e30f;
    #pragma unroll
    for (int i = 0; i < 8; ++i) { v[i] = bf2f(raw.u[i]); m = fmaxf(m, v[i]); }
    #pragma unroll
    for (int off = 32; off > 0; off >>= 1) m = fmaxf(m, __shfl_xor(m, off));
    float sum = 0.f;
    #pragma unroll
    for (int i = 0; i < 8; ++i) sum += expf(v[i] - m);
    #pragma unroll
    for (int off = 32; off > 0; off >>= 1) sum += __shfl_xor(sum, off);
    float lse = m + logf(sum);
    int tgt = obs_idx[s];
    float tv = 0.f;
    #pragma unroll
    for (int i = 0; i < 8; ++i) if (lane * 8 + i == tgt) tv = v[i];
    #pragma unroll
    for (int off = 32; off > 0; off >>= 1) tv += __shfl_xor(tv, off);
    if (lane == 0) atomicAdd(&ce_acc[s >> 8], lse - tv);
}

// ---------------------------------------------------------------- reward / continue heads
__global__ void k_heads(const unsigned short* __restrict__ dec1,
                        const float* __restrict__ Wr2, const float* __restrict__ br2,
                        const float* __restrict__ Wc2, const float* __restrict__ bc2,
                        const float* __restrict__ rew, const float* __restrict__ done,
                        float* __restrict__ mse_acc, float* __restrict__ bce_acc) {
    int s = (blockIdx.x * 256 + threadIdx.x) >> 6;
    int lane = threadIdx.x & 63;
    float vr = bf2f(dec1[(size_t)s * 192 + 64 + lane]) * Wr2[lane];
    float vc = bf2f(dec1[(size_t)s * 192 + 128 + lane]) * Wc2[lane];
    #pragma unroll
    for (int off = 32; off > 0; off >>= 1) {
        vr += __shfl_xor(vr, off);
        vc += __shfl_xor(vc, off);
    }
    if (lane == 0) {
        float r_pred = vr + br2[0], c_pred = vc + bc2[0];
        float rt = rew[s];
        float sgn = (rt > 0.f) ? 1.f : ((rt < 0.f) ? -1.f : 0.f);
        float r_tgt = sgn * log1pf(fabsf(rt));
        float d = r_pred - r_tgt;
        float ct = 1.f - done[s];
        float bce = fmaxf(c_pred, 0.f) - c_pred * ct + log1pf(expf(-fabsf(c_pred)));
        atomicAdd(&mse_acc[s >> 8], d * d);
        atomicAdd(&bce_acc[s >> 8], bce);
    }
}

// ---------------------------------------------------------------- final reduce
__global__ void k_final(const float* __restrict__ ce_acc, const float* __restrict__ mse_acc,
                        const float* __restrict__ bce_acc, const float* __restrict__ kl_acc,
                        float* __restrict__ out) {
    int t = threadIdx.x;
    float ce = ce_acc[t] * (1.f / 256.f);
    float ms = mse_acc[t] * (1.f / 256.f);
    float bc = bce_acc[t] * (1.f / 256.f);
    float ka = kl_acc[t] * (1.f / 256.f);
    float kt = fmaxf(ka, 1.f);
    #pragma unroll
    for (int off = 32; off > 0; off >>= 1) {
        ce += __shfl_down(ce, off);
        ms += __shfl_down(ms, off);
        bc += __shfl_down(bc, off);
        kt += __shfl_down(kt, off);
    }
    if (t == 0) {
        ce *= (1.f / 64.f); ms *= (1.f / 64.f); bc *= (1.f / 64.f); kt *= (1.f / 64.f);
        out[0] = ce + ms + bc + kt;
        out[1] = ce; out[2] = ms; out[3] = bc; out[4] = kt;
    }
}

// ----------------------------------------------------------------------------------
extern "C" void kernel_launch(void* const* d_in, const int* in_sizes, int n_in,
                              void* d_out, int out_size, void* d_ws, size_t ws_size,
                              hipStream_t stream) {
    const float* obs  = (const float*)d_in[0];
    const float* act  = (const float*)d_in[1];
    const float* rew  = (const float*)d_in[2];
    const float* done = (const float*)d_in[3];
    const float* gum  = (const float*)d_in[4];
    const float* We1  = (const float*)d_in[5];
    const float* be1  = (const float*)d_in[6];
    const float* We2  = (const float*)d_in[7];
    const float* be2  = (const float*)d_in[8];
    const float* Wi   = (const float*)d_in[9];
    const float* Wh   = (const float*)d_in[10];
    const float* bi   = (const float*)d_in[11];
    const float* bh   = (const float*)d_in[12];
    const float* Wp1  = (const float*)d_in[13];
    const float* bp1  = (const float*)d_in[14];
    const float* Wp2  = (const float*)d_in[15];
    const float* bp2  = (const float*)d_in[16];
    const float* Wq1  = (const float*)d_in[17];
    const float* bq1  = (const float*)d_in[18];
    const float* Wq2  = (const float*)d_in[19];
    const float* bq2  = (const float*)d_in[20];
    const float* Wd1  = (const float*)d_in[21];
    const float* bd1  = (const float*)d_in[22];
    const float* Wd2  = (const float*)d_in[23];
    const float* bd2  = (const float*)d_in[24];
    const float* Wr1  = (const float*)d_in[25];
    const float* br1  = (const float*)d_in[26];
    const float* Wr2  = (const float*)d_in[27];
    const float* br2  = (const float*)d_in[28];
    const float* Wc1  = (const float*)d_in[29];
    const float* bc1  = (const float*)d_in[30];
    const float* Wc2  = (const float*)d_in[31];
    const float* bc2  = (const float*)d_in[32];

    char* base = (char*)d_ws;
    size_t off = 0;
    auto alloc = [&](size_t bytes) -> char* {
        char* p = base + off;
        off += (bytes + 255) & ~(size_t)255;
        return p;
    };
    unsigned short* WcatT = (unsigned short*)alloc(3072u * 2048 * 2);   // 12.6 MB
    unsigned short* Wq1aT = (unsigned short*)alloc(1024u * 1024 * 2);
    unsigned short* Wq1bT = (unsigned short*)alloc(1024u * 512 * 2);
    unsigned short* Wq2T  = (unsigned short*)alloc(1024u * 1024 * 2);
    unsigned short* Wp1T  = (unsigned short*)alloc(1024u * 1024 * 2);
    unsigned short* Wp2T  = (unsigned short*)alloc(1024u * 1024 * 2);
    unsigned short* WdrcT = (unsigned short*)alloc(192u * 2048 * 2);
    unsigned short* Wd2T  = (unsigned short*)alloc(512u * 64 * 2);
    unsigned short* We2T  = (unsigned short*)alloc(512u * 64 * 2);
    float*          b_drc = (float*)alloc(192 * 4);
    unsigned short* XZ    = (unsigned short*)alloc(65u * 256 * 2048 * 2);  // 68 MB
    float*          h_st  = (float*)alloc(256u * 1024 * 4);
    unsigned short* post1 = (unsigned short*)alloc(256u * 1024 * 2);
    unsigned short* postL = (unsigned short*)alloc(16384u * 1024 * 2);     // 32 MB (reused as logits)
    unsigned short* Eq    = (unsigned short*)alloc(16384u * 1024 * 2);     // 32 MB (reused as priorL)
    unsigned short* pri1  = (unsigned short*)alloc(16384u * 1024 * 2);     // 32 MB
    unsigned short* dec1  = (unsigned short*)alloc(16384u * 192 * 2);
    float*          acc   = (float*)alloc(256 * 4);
    int*            obs_idx = (int*)alloc(16384 * 4);
    int*            act_idx = (int*)alloc(16384 * 4);
    unsigned short* embed = pri1;                    // setup-time aliases
    unsigned short* e1    = pri1 + 16384u * 512;

    hipMemsetAsync(XZ, 0, 256u * 2048 * 2, stream);
    hipMemsetAsync(h_st, 0, 256u * 1024 * 4, stream);
    hipMemsetAsync(acc, 0, 256 * 4, stream);

    k_idx<<<4096, 256, 0, stream>>>(obs, act, obs_idx, act_idx);

    dim3 tb(32, 8);
    for (int g = 0; g < 3; ++g) {
        k_transp<<<dim3(32, 32), tb, 0, stream>>>(Wh + g * 1024, 3072,
                                                  WcatT + (size_t)g * 1024 * 2048, 2048, 0);
        k_transp<<<dim3(32, 32), tb, 0, stream>>>(Wi + g * 1024, 3072,
                                                  WcatT + (size_t)g * 1024 * 2048, 2048, 1024);
    }
    k_transp<<<dim3(32, 32), tb, 0, stream>>>(Wq1, 1024, Wq1aT, 1024, 0);
    k_transp<<<dim3(32, 16), tb, 0, stream>>>(Wq1 + 1024u * 1024, 1024, Wq1bT, 512, 0);
    k_transp<<<dim3(32, 32), tb, 0, stream>>>(Wq2, 1024, Wq2T, 1024, 0);
    k_transp<<<dim3(32, 32), tb, 0, stream>>>(Wp1, 1024, Wp1T, 1024, 0);
    k_transp<<<dim3(32, 32), tb, 0, stream>>>(Wp2, 1024, Wp2T, 1024, 0);
    k_transp<<<dim3(2, 64),  tb, 0, stream>>>(Wd1, 64, WdrcT, 2048, 0);
    k_transp<<<dim3(2, 64),  tb, 0, stream>>>(Wr1, 64, WdrcT + 64u * 2048, 2048, 0);
    k_transp<<<dim3(2, 64),  tb, 0, stream>>>(Wc1, 64, WdrcT + 128u * 2048, 2048, 0);
    k_transp<<<dim3(16, 2),  tb, 0, stream>>>(Wd2, 512, Wd2T, 64, 0);
    k_transp<<<dim3(16, 2),  tb, 0, stream>>>(We2, 512, We2T, 64, 0);
    k_pack_bias<<<1, 192, 0, stream>>>(bd1, br1, bc1, b_drc);

    // embed & Eq precompute
    k_e1<<<4096, 256, 0, stream>>>(obs_idx, We1, be1, e1);
    {
        MJob m = { e1, 64, We2T, be2, nullptr, embed, 512, 512, 64, 2 };
        mfma_gemm<<<dim3(8, 256), 256, 0, stream>>>(m);
    }
    {
        MJob m = { embed, 512, Wq1bT, bq1, nullptr, Eq, 1024, 1024, 512, 2 };
        mfma_gemm<<<dim3(16, 256), 256, 0, stream>>>(m);
    }

    // serial scan: 3 kernels/step
    for (int t = 1; t <= TT; ++t) {
        unsigned short* xz_prev = XZ + (size_t)(t - 1) * 256 * 2048;
        unsigned short* xz_cur  = XZ + (size_t)t * 256 * 2048;
        k_scan1<<<dim3(16, 4), 256, 0, stream>>>(xz_prev, WcatT, Wi, bi, bh,
                                                 act_idx + (t - 1) * 256, h_st, xz_cur);
        k_post1<<<dim3(16, 4), 256, 0, stream>>>(xz_cur, Wq1aT,
                                                 Eq + (size_t)(t - 1) * 262144, post1);
        k_postL<<<dim3(16, 4), 256, 0, stream>>>(post1, Wq2T, bq2,
                                                 gum + (size_t)(t - 1) * 262144,
                                                 postL + (size_t)(t - 1) * 262144, xz_cur);
    }

    // deferred batched passes
    unsigned short* Hall = XZ + (size_t)256 * 2048;
    {
        MJob m = { Hall, 2048, Wp1T, bp1, nullptr, pri1, 1024, 1024, 1024, 1 | 2 };
        mfma_gemm<<<dim3(16, 256), 256, 0, stream>>>(m);
    }
    {
        MJob m = { pri1, 1024, Wp2T, bp2, nullptr, Eq, 1024, 1024, 1024, 2 };
        mfma_gemm<<<dim3(16, 256), 256, 0, stream>>>(m);
    }
    k_kl<<<2048, 256, 0, stream>>>(postL, Eq, acc + 192);
    {
        MJob m = { Hall, 2048, WdrcT, b_drc, nullptr, dec1, 192, 192, 2048, 1 | 2 };
        mfma_gemm<<<dim3(3, 256), 256, 0, stream>>>(m);
    }
    {
        MJob m = { dec1, 192, Wd2T, bd2, nullptr, postL, 512, 512, 64, 2 };
        mfma_gemm<<<dim3(8, 256), 256, 0, stream>>>(m);
    }
    k_ce<<<4096, 256, 0, stream>>>(postL, obs_idx, acc + 0);
    k_heads<<<4096, 256, 0, stream>>>(dec1, Wr2, br2, Wc2, bc2, rew, done,
                                      acc + 64, acc + 128);
    k_final<<<1, 64, 0, stream>>>(acc + 0, acc + 64, acc + 128, acc + 192, (float*)d_out);
}